// Round 2
// baseline (588.797 us; speedup 1.0000x reference)
//
#include <hip/hip_runtime.h>
#include <hip/hip_bf16.h>

// Transformer block: B=4 T=2048 C=384 H=6 HS=64.
// Reference softmax is over the QUERY axis -> w[t,s] = exp(S[t,s])/colsum[s],
// colsum[s] = sum_{t>=s} exp(S[t,s]).  Pipeline: colsum pass, then out = E @ (V/colsum).
//
// WS BUDGET: round-1 used ~92.5MB unchecked and corrupted neighboring device
// allocations (first launch passed, replays-from-pristine diverged). This round
// overlays buffer lifetimes + chunks the MLP: peak ws = ~27.6 MiB.

#define BB 4
#define TT 2048
#define CC 384
#define HH 6
#define HS 64
#define BT 8192
#define C4 1536
#define SCALE 0.05103103630798288f   // 384^-0.5

typedef __attribute__((ext_vector_type(8))) short short8;   // 8 x bf16
typedef __attribute__((ext_vector_type(4))) float f32x4;
typedef __hip_bfloat16 bf16_t;

__device__ inline short8 ld8(const bf16_t* p) { return *reinterpret_cast<const short8*>(p); }
#define MFMA(a, b, c) __builtin_amdgcn_mfma_f32_16x16x32_bf16(a, b, c, 0, 0, 0)

// ---------------- weight transpose + cast: dst[b][c][r] = src[b][r][c] ----------------
__global__ __launch_bounds__(256) void tcast_kernel(const float* __restrict__ src,
                                                    bf16_t* __restrict__ dst,
                                                    int R, int Cc, int total) {
    int idx = blockIdx.x * 256 + threadIdx.x;
    if (idx >= total) return;
    int rc = R * Cc;
    int b = idx / rc;
    int rem = idx - b * rc;
    int r = rem / Cc;
    int c = rem - r * Cc;
    dst[b * rc + c * R + r] = __float2bfloat16(src[idx]);
}

// ---------------- LayerNorm: one wave per row of 384 ----------------
__global__ __launch_bounds__(256) void ln_kernel(const float* __restrict__ x,
                                                 const float* __restrict__ g,
                                                 const float* __restrict__ be,
                                                 bf16_t* __restrict__ out) {
    int wave = threadIdx.x >> 6, lane = threadIdx.x & 63;
    int row = blockIdx.x * 4 + wave;
    const float* xr = x + (size_t)row * CC;
    float v[6];
    float s = 0.f;
#pragma unroll
    for (int i = 0; i < 6; i++) { v[i] = xr[lane + i * 64]; s += v[i]; }
#pragma unroll
    for (int off = 32; off > 0; off >>= 1) s += __shfl_xor(s, off, 64);
    float mean = s * (1.f / 384.f);
    float s2 = 0.f;
#pragma unroll
    for (int i = 0; i < 6; i++) { float d = v[i] - mean; s2 += d * d; }
#pragma unroll
    for (int off = 32; off > 0; off >>= 1) s2 += __shfl_xor(s2, off, 64);
    float rstd = rsqrtf(s2 * (1.f / 384.f) + 1e-5f);
    bf16_t* orow = out + (size_t)row * CC;
#pragma unroll
    for (int i = 0; i < 6; i++) {
        int c = lane + i * 64;
        orow[c] = __float2bfloat16((v[i] - mean) * rstd * g[c] + be[c]);
    }
}

// ---------------- 64x64 MFMA tile core. A: MxK row-major. Bt: NxK row-major (B transposed). ----------------
// A-frag: A[m=lane&15][k=quad*8+j]; B-frag: Bt[n=lane&15][k=quad*8+j]; D: row=quad*4+reg, col=lane&15.
__device__ inline void gemm_core(const bf16_t* __restrict__ A, const bf16_t* __restrict__ Bt,
                                 int m0, int n0, int lda, int ldb, int K, f32x4 acc[2][2]) {
    const int lane = threadIdx.x & 63;
    const int wave = threadIdx.x >> 6;
    const int wm = (wave >> 1) * 32, wn = (wave & 1) * 32;
    const int r16 = lane & 15, quad = lane >> 4;
    const bf16_t* Ap = A + (size_t)(m0 + wm + r16) * lda + quad * 8;
    const bf16_t* Bp = Bt + (size_t)(n0 + wn + r16) * ldb + quad * 8;
    for (int k = 0; k < K; k += 32) {
        short8 a0 = ld8(Ap + k);
        short8 a1 = ld8(Ap + (size_t)16 * lda + k);
        short8 b0 = ld8(Bp + k);
        short8 b1 = ld8(Bp + (size_t)16 * ldb + k);
        acc[0][0] = MFMA(a0, b0, acc[0][0]);
        acc[0][1] = MFMA(a0, b1, acc[0][1]);
        acc[1][0] = MFMA(a1, b0, acc[1][0]);
        acc[1][1] = MFMA(a1, b1, acc[1][1]);
    }
}

// ---------------- QKV projection: h(8192x384) @ per-head W(384x64) -> q,k bf16 + V^T bf16 ----------------
__global__ __launch_bounds__(256) void qkv_kernel(const bf16_t* __restrict__ hbf,
                                                  const bf16_t* __restrict__ wqt,
                                                  const bf16_t* __restrict__ wkt,
                                                  const bf16_t* __restrict__ wvt,
                                                  bf16_t* __restrict__ qbf,
                                                  bf16_t* __restrict__ kbf,
                                                  bf16_t* __restrict__ vt) {
    int mt = blockIdx.x, j = blockIdx.y;
    int mat = j / 6, head = j - mat * 6;
    const bf16_t* Bt = (mat == 0 ? wqt : (mat == 1 ? wkt : wvt)) + head * (HS * CC);
    f32x4 zero = {0.f, 0.f, 0.f, 0.f};
    f32x4 acc[2][2] = {{zero, zero}, {zero, zero}};
    gemm_core(hbf, Bt, mt * 64, 0, CC, CC, CC, acc);
    const int lane = threadIdx.x & 63, wave = threadIdx.x >> 6;
    const int wm = (wave >> 1) * 32, wn = (wave & 1) * 32;
    const int col = lane & 15, quad = lane >> 4;
#pragma unroll
    for (int mi = 0; mi < 2; mi++)
#pragma unroll
        for (int ni = 0; ni < 2; ni++)
#pragma unroll
            for (int reg = 0; reg < 4; reg++) {
                int m = mt * 64 + wm + mi * 16 + quad * 4 + reg;
                int d = wn + ni * 16 + col;
                int b = m >> 11, t = m & 2047;
                int bh = b * HH + head;
                float val = acc[mi][ni][reg];
                if (mat == 0)      qbf[(size_t)(bh * TT + t) * HS + d] = __float2bfloat16(val);
                else if (mat == 1) kbf[(size_t)(bh * TT + t) * HS + d] = __float2bfloat16(val);
                else               vt[(size_t)(bh * HS + d) * TT + t] = __float2bfloat16(val);
            }
}

// ---------------- colsum[s] = sum_{t>=s} exp(q[t].k[s]*scale) ----------------
__global__ __launch_bounds__(256) void colsum_kernel(const bf16_t* __restrict__ qbf,
                                                     const bf16_t* __restrict__ kbf,
                                                     float* __restrict__ colsum) {
    int stile = blockIdx.x, bh = blockIdx.y;
    int s0 = stile * 64;
    const int lane = threadIdx.x & 63, wave = threadIdx.x >> 6;
    const int r16 = lane & 15, quad = lane >> 4;
    __shared__ float csum[64];
    if (threadIdx.x < 64) csum[threadIdx.x] = 0.f;
    __syncthreads();
    short8 bfr[4][2];
#pragma unroll
    for (int ns = 0; ns < 4; ns++)
#pragma unroll
        for (int kk = 0; kk < 2; kk++)
            bfr[ns][kk] = ld8(kbf + (size_t)(bh * TT + s0 + ns * 16 + r16) * HS + kk * 32 + quad * 8);
    float colacc[4] = {0.f, 0.f, 0.f, 0.f};
    for (int tt = stile + wave; tt < 32; tt += 4) {
#pragma unroll
        for (int ms = 0; ms < 4; ms++) {
            const bf16_t* qp = qbf + (size_t)(bh * TT + tt * 64 + ms * 16 + r16) * HS + quad * 8;
            short8 a0 = ld8(qp);
            short8 a1 = ld8(qp + 32);
#pragma unroll
            for (int ns = 0; ns < 4; ns++) {
                f32x4 sacc = {0.f, 0.f, 0.f, 0.f};
                sacc = MFMA(a0, bfr[ns][0], sacc);
                sacc = MFMA(a1, bfr[ns][1], sacc);
#pragma unroll
                for (int reg = 0; reg < 4; reg++) {
                    int t = tt * 64 + ms * 16 + quad * 4 + reg;
                    int s = s0 + ns * 16 + r16;
                    if (s <= t) colacc[ns] += __expf(sacc[reg] * SCALE);
                }
            }
        }
    }
#pragma unroll
    for (int ns = 0; ns < 4; ns++) atomicAdd(&csum[ns * 16 + r16], colacc[ns]);
    __syncthreads();
    if (threadIdx.x < 64) colsum[bh * TT + s0 + threadIdx.x] = csum[threadIdx.x];
}

// ---------------- in-place: vst[bh][d][s] /= colsum[bh][s] ----------------
__global__ __launch_bounds__(256) void vscale_kernel(bf16_t* __restrict__ vst,
                                                     const float* __restrict__ colsum) {
    int idx = blockIdx.x * 256 + threadIdx.x;
    int s = idx & (TT - 1);
    int bh = idx >> 17;   // / (HS*TT)
    float v = __bfloat162float(vst[idx]);
    vst[idx] = __float2bfloat16(v / colsum[bh * TT + s]);
}

// ---------------- attention out: per 64-row t-tile, out = E @ Vs over s-tiles <= t-tile ----------------
__global__ __launch_bounds__(256) void attn_out_kernel(const bf16_t* __restrict__ qbf,
                                                       const bf16_t* __restrict__ kbf,
                                                       const bf16_t* __restrict__ vst,
                                                       bf16_t* __restrict__ attn) {
    int ttile = blockIdx.x, bh = blockIdx.y;
    int t0 = ttile * 64;
    const int lane = threadIdx.x & 63, wave = threadIdx.x >> 6;
    const int r16 = lane & 15, quad = lane >> 4;
    __shared__ bf16_t El[64][72];   // +8 pad: conflict-free b128 reads
    f32x4 zero = {0.f, 0.f, 0.f, 0.f};
    f32x4 oacc[4] = {zero, zero, zero, zero};
    const bf16_t* qp = qbf + (size_t)(bh * TT + t0 + wave * 16 + r16) * HS + quad * 8;
    short8 qa0 = ld8(qp);
    short8 qa1 = ld8(qp + 32);
    for (int st = 0; st <= ttile; st++) {
        int s0 = st * 64;
#pragma unroll
        for (int ns = 0; ns < 4; ns++) {
            const bf16_t* kp = kbf + (size_t)(bh * TT + s0 + ns * 16 + r16) * HS + quad * 8;
            f32x4 sacc = zero;
            sacc = MFMA(qa0, ld8(kp), sacc);
            sacc = MFMA(qa1, ld8(kp + 32), sacc);
#pragma unroll
            for (int reg = 0; reg < 4; reg++) {
                int t = t0 + wave * 16 + quad * 4 + reg;
                int s = s0 + ns * 16 + r16;
                float e = (s <= t) ? __expf(sacc[reg] * SCALE) : 0.f;
                El[wave * 16 + quad * 4 + reg][ns * 16 + r16] = __float2bfloat16(e);
            }
        }
        __syncthreads();
#pragma unroll
        for (int ks = 0; ks < 2; ks++) {
            short8 ea = ld8(&El[wave * 16 + r16][ks * 32 + quad * 8]);
#pragma unroll
            for (int ns = 0; ns < 4; ns++) {
                short8 vb = ld8(vst + (size_t)(bh * HS + ns * 16 + r16) * TT + s0 + ks * 32 + quad * 8);
                oacc[ns] = MFMA(ea, vb, oacc[ns]);
            }
        }
        __syncthreads();
    }
    int b = bh / HH, head = bh - b * HH;
#pragma unroll
    for (int ns = 0; ns < 4; ns++)
#pragma unroll
        for (int reg = 0; reg < 4; reg++) {
            int t = t0 + wave * 16 + quad * 4 + reg;
            int d = ns * 16 + r16;
            attn[(size_t)(b * TT + t) * CC + head * HS + d] = __float2bfloat16(oacc[ns][reg]);
        }
}

// ---------------- generic GEMM + epilogue. MODE 0: +bias+resid -> fp32. MODE 1: +bias, relu -> bf16 ----------------
template <int KDIM, int MODE>
__global__ __launch_bounds__(256) void gemm_kernel(const bf16_t* __restrict__ A,
                                                   const bf16_t* __restrict__ Bt,
                                                   const float* __restrict__ bias,
                                                   const float* __restrict__ resid,
                                                   void* __restrict__ out, int N) {
    int mt = blockIdx.x, nt = blockIdx.y;
    f32x4 zero = {0.f, 0.f, 0.f, 0.f};
    f32x4 acc[2][2] = {{zero, zero}, {zero, zero}};
    gemm_core(A, Bt, mt * 64, nt * 64, KDIM, KDIM, KDIM, acc);
    const int lane = threadIdx.x & 63, wave = threadIdx.x >> 6;
    const int wm = (wave >> 1) * 32, wn = (wave & 1) * 32;
    const int col = lane & 15, quad = lane >> 4;
#pragma unroll
    for (int mi = 0; mi < 2; mi++)
#pragma unroll
        for (int ni = 0; ni < 2; ni++)
#pragma unroll
            for (int reg = 0; reg < 4; reg++) {
                int m = mt * 64 + wm + mi * 16 + quad * 4 + reg;
                int n = nt * 64 + wn + ni * 16 + col;
                float val = acc[mi][ni][reg] + bias[n];
                if (MODE == 0)
                    ((float*)out)[(size_t)m * N + n] = val + resid[(size_t)m * N + n];
                else
                    ((bf16_t*)out)[(size_t)m * N + n] = __float2bfloat16(fmaxf(val, 0.f));
            }
}

extern "C" void kernel_launch(void* const* d_in, const int* in_sizes, int n_in,
                              void* d_out, int out_size, void* d_ws, size_t ws_size,
                              hipStream_t stream) {
    const float* x      = (const float*)d_in[0];
    const float* wq     = (const float*)d_in[1];
    const float* wk     = (const float*)d_in[2];
    const float* wv     = (const float*)d_in[3];
    const float* w_proj = (const float*)d_in[4];
    const float* b_proj = (const float*)d_in[5];
    const float* w1     = (const float*)d_in[6];
    const float* b1     = (const float*)d_in[7];
    const float* w2     = (const float*)d_in[8];
    const float* b2     = (const float*)d_in[9];
    const float* g1     = (const float*)d_in[10];
    const float* be1    = (const float*)d_in[11];
    const float* g2     = (const float*)d_in[12];
    const float* be2    = (const float*)d_in[13];
    float* out = (float*)d_out;

    // ---- overlayed workspace plan (peak ~27.6 MiB) ----
    char* p = (char*)d_ws;
    auto alloc = [&](size_t bytes) {
        void* r = (void*)p;
        p += (bytes + 255) & ~(size_t)255;
        return r;
    };
    const size_t ACT  = (size_t)BT * CC * 2;      // 6291456 B, one bf16 activation
    bf16_t* wqt    = (bf16_t*)alloc(HH * HS * CC * 2);
    bf16_t* wkt    = (bf16_t*)alloc(HH * HS * CC * 2);
    bf16_t* wvt    = (bf16_t*)alloc(HH * HS * CC * 2);
    bf16_t* wpt    = (bf16_t*)alloc(CC * CC * 2);
    bf16_t* w1t    = (bf16_t*)alloc((size_t)C4 * CC * 2);
    bf16_t* w2t    = (bf16_t*)alloc((size_t)CC * C4 * 2);
    float*  colsum = (float*) alloc((size_t)24 * TT * 4);
    // slotA: h_bf (steps 2-3) -> attn (6-7) -> f1 chunk (9-10)
    char* slotA = (char*)alloc(ACT);
    // slotB: q_bf+k_bf (3-6) -> x1 fp32 (7-10)
    char* slotB = (char*)alloc(2 * ACT);
    // slotC: v_bf transposed (3-6) -> h2_bf (8-9)
    char* slotC = (char*)alloc(ACT);

    bf16_t* h_bf  = (bf16_t*)slotA;
    bf16_t* attn  = (bf16_t*)slotA;
    bf16_t* f1    = (bf16_t*)slotA;           // 2048 x 1536 bf16 chunk = 6291456 B
    bf16_t* q_bf  = (bf16_t*)slotB;
    bf16_t* k_bf  = (bf16_t*)(slotB + ACT);
    float*  x1    = (float*)slotB;            // 8192 x 384 fp32 = 12582912 B = 2*ACT
    bf16_t* v_bf  = (bf16_t*)slotC;           // [bh][d][t]
    bf16_t* h2_bf = (bf16_t*)slotC;

    // 1. weight transpose+cast (weights persistent, never overlaid)
    tcast_kernel<<<(HH*CC*HS + 255)/256, 256, 0, stream>>>(wq, wqt, CC, HS, HH*CC*HS);
    tcast_kernel<<<(HH*CC*HS + 255)/256, 256, 0, stream>>>(wk, wkt, CC, HS, HH*CC*HS);
    tcast_kernel<<<(HH*CC*HS + 255)/256, 256, 0, stream>>>(wv, wvt, CC, HS, HH*CC*HS);
    tcast_kernel<<<(CC*CC + 255)/256, 256, 0, stream>>>(w_proj, wpt, CC, CC, CC*CC);
    tcast_kernel<<<(CC*C4 + 255)/256, 256, 0, stream>>>(w1, w1t, CC, C4, CC*C4);
    tcast_kernel<<<(C4*CC + 255)/256, 256, 0, stream>>>(w2, w2t, C4, CC, C4*CC);
    // 2. LN1
    ln_kernel<<<BT/4, 256, 0, stream>>>(x, g1, be1, h_bf);
    // 3. QKV
    qkv_kernel<<<dim3(BT/64, 18), 256, 0, stream>>>(h_bf, wqt, wkt, wvt, q_bf, k_bf, v_bf);
    // 4. column sums of exp(scores)
    colsum_kernel<<<dim3(32, 24), 256, 0, stream>>>(q_bf, k_bf, colsum);
    // 5. V /= colsum (in place)
    vscale_kernel<<<(24*HS*TT)/256, 256, 0, stream>>>(v_bf, colsum);
    // 6. attention output (reads q,k,v; writes attn=slotA, h dead)
    attn_out_kernel<<<dim3(32, 24), 256, 0, stream>>>(q_bf, k_bf, v_bf, attn);
    // 7. proj + bias + residual -> x1 (overlays q+k, both dead)
    gemm_kernel<CC, 0><<<dim3(BT/64, CC/64), 256, 0, stream>>>(attn, wpt, b_proj, x, x1, CC);
    // 8. LN2 -> h2 (overlays v, dead)
    ln_kernel<<<BT/4, 256, 0, stream>>>(x1, g2, be2, h2_bf);
    // 9+10. MLP in 4 row-chunks of 2048 (f1 chunk overlays attn, dead)
    for (int c = 0; c < 4; c++) {
        size_t m0 = (size_t)c * 2048;
        gemm_kernel<CC, 1><<<dim3(2048/64, C4/64), 256, 0, stream>>>(
            h2_bf + m0 * CC, w1t, b1, nullptr, f1, C4);
        gemm_kernel<C4, 0><<<dim3(2048/64, CC/64), 256, 0, stream>>>(
            f1, w2t, b2, x1 + m0 * CC, out + m0 * CC, CC);
    }
}

// Round 5
// 585.244 us; speedup vs baseline: 1.0061x; 1.0061x over previous
//
#include <hip/hip_runtime.h>
#include <hip/hip_bf16.h>

// Transformer block: B=4 T=2048 C=384 H=6 HS=64.
// Reference softmax is over the QUERY axis -> w[t,s] = exp(S[t,s])/colsum[s],
// colsum[s] = sum_{t>=s} exp(S[t,s]).  Pipeline: colsum pass, then out = E @ (V/colsum).
//
// R5: reverted to R2-proven colsum/attn math + memory plan (28,901,376 B, passed).
// R3/R4's split-K+atomic rewrite had a deterministic bug (identical absmax across
// two memory layouts) — abandoned. This round's changes to attn only:
//  (a) no per-iteration __syncthreads: the El tile is wave-private (each wave
//      writes and reads only rows [wave*16, wave*16+16)) — parity double-buffer
//      kills the cross-iteration WAR window;
//  (b) LPT: ttile = 31 - blockIdx.x so longest blocks launch first (R2 showed
//      18.4% avg occupancy = dispatch drain).

#define BB 4
#define TT 2048
#define CC 384
#define HH 6
#define HS 64
#define BT 8192
#define C4 1536
#define SCALE 0.05103103630798288f   // 384^-0.5

typedef __attribute__((ext_vector_type(8))) short short8;   // 8 x bf16
typedef __attribute__((ext_vector_type(4))) float f32x4;
typedef __hip_bfloat16 bf16_t;

__device__ inline short8 ld8(const bf16_t* p) { return *reinterpret_cast<const short8*>(p); }
#define MFMA(a, b, c) __builtin_amdgcn_mfma_f32_16x16x32_bf16(a, b, c, 0, 0, 0)

// ---------------- weight transpose + cast: dst[b][c][r] = src[b][r][c] ----------------
__global__ __launch_bounds__(256) void tcast_kernel(const float* __restrict__ src,
                                                    bf16_t* __restrict__ dst,
                                                    int R, int Cc, int total) {
    int idx = blockIdx.x * 256 + threadIdx.x;
    if (idx >= total) return;
    int rc = R * Cc;
    int b = idx / rc;
    int rem = idx - b * rc;
    int r = rem / Cc;
    int c = rem - r * Cc;
    dst[b * rc + c * R + r] = __float2bfloat16(src[idx]);
}

// ---------------- LayerNorm: one wave per row of 384 ----------------
__global__ __launch_bounds__(256) void ln_kernel(const float* __restrict__ x,
                                                 const float* __restrict__ g,
                                                 const float* __restrict__ be,
                                                 bf16_t* __restrict__ out) {
    int wave = threadIdx.x >> 6, lane = threadIdx.x & 63;
    int row = blockIdx.x * 4 + wave;
    const float* xr = x + (size_t)row * CC;
    float v[6];
    float s = 0.f;
#pragma unroll
    for (int i = 0; i < 6; i++) { v[i] = xr[lane + i * 64]; s += v[i]; }
#pragma unroll
    for (int off = 32; off > 0; off >>= 1) s += __shfl_xor(s, off, 64);
    float mean = s * (1.f / 384.f);
    float s2 = 0.f;
#pragma unroll
    for (int i = 0; i < 6; i++) { float d = v[i] - mean; s2 += d * d; }
#pragma unroll
    for (int off = 32; off > 0; off >>= 1) s2 += __shfl_xor(s2, off, 64);
    float rstd = rsqrtf(s2 * (1.f / 384.f) + 1e-5f);
    bf16_t* orow = out + (size_t)row * CC;
#pragma unroll
    for (int i = 0; i < 6; i++) {
        int c = lane + i * 64;
        orow[c] = __float2bfloat16((v[i] - mean) * rstd * g[c] + be[c]);
    }
}

// ---------------- 64x64 MFMA tile core. A: MxK row-major. Bt: NxK row-major (B transposed). ----------------
// A-frag: A[m=lane&15][k=quad*8+j]; B-frag: Bt[n=lane&15][k=quad*8+j]; D: row=quad*4+reg, col=lane&15.
__device__ inline void gemm_core(const bf16_t* __restrict__ A, const bf16_t* __restrict__ Bt,
                                 int m0, int n0, int lda, int ldb, int K, f32x4 acc[2][2]) {
    const int lane = threadIdx.x & 63;
    const int wave = threadIdx.x >> 6;
    const int wm = (wave >> 1) * 32, wn = (wave & 1) * 32;
    const int r16 = lane & 15, quad = lane >> 4;
    const bf16_t* Ap = A + (size_t)(m0 + wm + r16) * lda + quad * 8;
    const bf16_t* Bp = Bt + (size_t)(n0 + wn + r16) * ldb + quad * 8;
    for (int k = 0; k < K; k += 32) {
        short8 a0 = ld8(Ap + k);
        short8 a1 = ld8(Ap + (size_t)16 * lda + k);
        short8 b0 = ld8(Bp + k);
        short8 b1 = ld8(Bp + (size_t)16 * ldb + k);
        acc[0][0] = MFMA(a0, b0, acc[0][0]);
        acc[0][1] = MFMA(a0, b1, acc[0][1]);
        acc[1][0] = MFMA(a1, b0, acc[1][0]);
        acc[1][1] = MFMA(a1, b1, acc[1][1]);
    }
}

// ---------------- QKV projection: h(8192x384) @ per-head W(384x64) -> q,k bf16 + V^T bf16 ----------------
__global__ __launch_bounds__(256) void qkv_kernel(const bf16_t* __restrict__ hbf,
                                                  const bf16_t* __restrict__ wqt,
                                                  const bf16_t* __restrict__ wkt,
                                                  const bf16_t* __restrict__ wvt,
                                                  bf16_t* __restrict__ qbf,
                                                  bf16_t* __restrict__ kbf,
                                                  bf16_t* __restrict__ vt) {
    int mt = blockIdx.x, j = blockIdx.y;
    int mat = j / 6, head = j - mat * 6;
    const bf16_t* Bt = (mat == 0 ? wqt : (mat == 1 ? wkt : wvt)) + head * (HS * CC);
    f32x4 zero = {0.f, 0.f, 0.f, 0.f};
    f32x4 acc[2][2] = {{zero, zero}, {zero, zero}};
    gemm_core(hbf, Bt, mt * 64, 0, CC, CC, CC, acc);
    const int lane = threadIdx.x & 63, wave = threadIdx.x >> 6;
    const int wm = (wave >> 1) * 32, wn = (wave & 1) * 32;
    const int col = lane & 15, quad = lane >> 4;
#pragma unroll
    for (int mi = 0; mi < 2; mi++)
#pragma unroll
        for (int ni = 0; ni < 2; ni++)
#pragma unroll
            for (int reg = 0; reg < 4; reg++) {
                int m = mt * 64 + wm + mi * 16 + quad * 4 + reg;
                int d = wn + ni * 16 + col;
                int b = m >> 11, t = m & 2047;
                int bh = b * HH + head;
                float val = acc[mi][ni][reg];
                if (mat == 0)      qbf[(size_t)(bh * TT + t) * HS + d] = __float2bfloat16(val);
                else if (mat == 1) kbf[(size_t)(bh * TT + t) * HS + d] = __float2bfloat16(val);
                else               vt[(size_t)(bh * HS + d) * TT + t] = __float2bfloat16(val);
            }
}

// ---------------- colsum[s] = sum_{t>=s} exp(q[t].k[s]*scale)  (R2-proven) ----------------
__global__ __launch_bounds__(256) void colsum_kernel(const bf16_t* __restrict__ qbf,
                                                     const bf16_t* __restrict__ kbf,
                                                     float* __restrict__ colsum) {
    int stile = blockIdx.x, bh = blockIdx.y;
    int s0 = stile * 64;
    const int lane = threadIdx.x & 63, wave = threadIdx.x >> 6;
    const int r16 = lane & 15, quad = lane >> 4;
    __shared__ float csum[64];
    if (threadIdx.x < 64) csum[threadIdx.x] = 0.f;
    __syncthreads();
    short8 bfr[4][2];
#pragma unroll
    for (int ns = 0; ns < 4; ns++)
#pragma unroll
        for (int kk = 0; kk < 2; kk++)
            bfr[ns][kk] = ld8(kbf + (size_t)(bh * TT + s0 + ns * 16 + r16) * HS + kk * 32 + quad * 8);
    float colacc[4] = {0.f, 0.f, 0.f, 0.f};
    for (int tt = stile + wave; tt < 32; tt += 4) {
#pragma unroll
        for (int ms = 0; ms < 4; ms++) {
            const bf16_t* qp = qbf + (size_t)(bh * TT + tt * 64 + ms * 16 + r16) * HS + quad * 8;
            short8 a0 = ld8(qp);
            short8 a1 = ld8(qp + 32);
#pragma unroll
            for (int ns = 0; ns < 4; ns++) {
                f32x4 sacc = {0.f, 0.f, 0.f, 0.f};
                sacc = MFMA(a0, bfr[ns][0], sacc);
                sacc = MFMA(a1, bfr[ns][1], sacc);
#pragma unroll
                for (int reg = 0; reg < 4; reg++) {
                    int t = tt * 64 + ms * 16 + quad * 4 + reg;
                    int s = s0 + ns * 16 + r16;
                    if (s <= t) colacc[ns] += __expf(sacc[reg] * SCALE);
                }
            }
        }
    }
#pragma unroll
    for (int ns = 0; ns < 4; ns++) atomicAdd(&csum[ns * 16 + r16], colacc[ns]);
    __syncthreads();
    if (threadIdx.x < 64) colsum[bh * TT + s0 + threadIdx.x] = csum[threadIdx.x];
}

// ---------------- in-place: vst[bh][d][s] /= colsum[bh][s] ----------------
__global__ __launch_bounds__(256) void vscale_kernel(bf16_t* __restrict__ vst,
                                                     const float* __restrict__ colsum) {
    int idx = blockIdx.x * 256 + threadIdx.x;
    int s = idx & (TT - 1);
    int bh = idx >> 17;   // / (HS*TT)
    float v = __bfloat162float(vst[idx]);
    vst[idx] = __float2bfloat16(v / colsum[bh * TT + s]);
}

// ---------------- attention out: per 64-row t-tile, out = E @ Vs over s-tiles <= t-tile ----------------
// R5: barrier-free (El rows are wave-private; parity double-buffer breaks the
// cross-iteration WAR), LPT order (longest t-tiles launch first).
__global__ __launch_bounds__(256) void attn_out_kernel(const bf16_t* __restrict__ qbf,
                                                       const bf16_t* __restrict__ kbf,
                                                       const bf16_t* __restrict__ vst,
                                                       bf16_t* __restrict__ attn) {
    int ttile = 31 - blockIdx.x, bh = blockIdx.y;   // LPT: block 0 = 32 iters
    int t0 = ttile * 64;
    const int lane = threadIdx.x & 63, wave = threadIdx.x >> 6;
    const int r16 = lane & 15, quad = lane >> 4;
    __shared__ bf16_t El[2][64][72];   // +8 pad; [2] = parity double buffer
    f32x4 zero = {0.f, 0.f, 0.f, 0.f};
    f32x4 oacc[4] = {zero, zero, zero, zero};
    const bf16_t* qp = qbf + (size_t)(bh * TT + t0 + wave * 16 + r16) * HS + quad * 8;
    short8 qa0 = ld8(qp);
    short8 qa1 = ld8(qp + 32);
    for (int st = 0; st <= ttile; st++) {
        int s0 = st * 64;
        bf16_t (*E)[72] = El[st & 1];
#pragma unroll
        for (int ns = 0; ns < 4; ns++) {
            const bf16_t* kp = kbf + (size_t)(bh * TT + s0 + ns * 16 + r16) * HS + quad * 8;
            f32x4 sacc = zero;
            sacc = MFMA(qa0, ld8(kp), sacc);
            sacc = MFMA(qa1, ld8(kp + 32), sacc);
#pragma unroll
            for (int reg = 0; reg < 4; reg++) {
                int t = t0 + wave * 16 + quad * 4 + reg;
                int s = s0 + ns * 16 + r16;
                float e = (s <= t) ? __expf(sacc[reg] * SCALE) : 0.f;
                E[wave * 16 + quad * 4 + reg][ns * 16 + r16] = __float2bfloat16(e);
            }
        }
        // no __syncthreads: rows [wave*16, wave*16+16) are written and read by
        // the same wave only; compiler orders the intra-wave LDS dependency.
#pragma unroll
        for (int ks = 0; ks < 2; ks++) {
            short8 ea = ld8(&E[wave * 16 + r16][ks * 32 + quad * 8]);
#pragma unroll
            for (int ns = 0; ns < 4; ns++) {
                short8 vb = ld8(vst + (size_t)(bh * HS + ns * 16 + r16) * TT + s0 + ks * 32 + quad * 8);
                oacc[ns] = MFMA(ea, vb, oacc[ns]);
            }
        }
    }
    int b = bh / HH, head = bh - b * HH;
#pragma unroll
    for (int ns = 0; ns < 4; ns++)
#pragma unroll
        for (int reg = 0; reg < 4; reg++) {
            int t = t0 + wave * 16 + quad * 4 + reg;
            int d = ns * 16 + r16;
            attn[(size_t)(b * TT + t) * CC + head * HS + d] = __float2bfloat16(oacc[ns][reg]);
        }
}

// ---------------- generic GEMM + epilogue. MODE 0: +bias+resid -> fp32. MODE 1: +bias, relu -> bf16 ----------------
template <int KDIM, int MODE>
__global__ __launch_bounds__(256) void gemm_kernel(const bf16_t* __restrict__ A,
                                                   const bf16_t* __restrict__ Bt,
                                                   const float* __restrict__ bias,
                                                   const float* __restrict__ resid,
                                                   void* __restrict__ out, int N) {
    int mt = blockIdx.x, nt = blockIdx.y;
    f32x4 zero = {0.f, 0.f, 0.f, 0.f};
    f32x4 acc[2][2] = {{zero, zero}, {zero, zero}};
    gemm_core(A, Bt, mt * 64, nt * 64, KDIM, KDIM, KDIM, acc);
    const int lane = threadIdx.x & 63, wave = threadIdx.x >> 6;
    const int wm = (wave >> 1) * 32, wn = (wave & 1) * 32;
    const int col = lane & 15, quad = lane >> 4;
#pragma unroll
    for (int mi = 0; mi < 2; mi++)
#pragma unroll
        for (int ni = 0; ni < 2; ni++)
#pragma unroll
            for (int reg = 0; reg < 4; reg++) {
                int m = mt * 64 + wm + mi * 16 + quad * 4 + reg;
                int n = nt * 64 + wn + ni * 16 + col;
                float val = acc[mi][ni][reg] + bias[n];
                if (MODE == 0)
                    ((float*)out)[(size_t)m * N + n] = val + resid[(size_t)m * N + n];
                else
                    ((bf16_t*)out)[(size_t)m * N + n] = __float2bfloat16(fmaxf(val, 0.f));
            }
}

extern "C" void kernel_launch(void* const* d_in, const int* in_sizes, int n_in,
                              void* d_out, int out_size, void* d_ws, size_t ws_size,
                              hipStream_t stream) {
    const float* x      = (const float*)d_in[0];
    const float* wq     = (const float*)d_in[1];
    const float* wk     = (const float*)d_in[2];
    const float* wv     = (const float*)d_in[3];
    const float* w_proj = (const float*)d_in[4];
    const float* b_proj = (const float*)d_in[5];
    const float* w1     = (const float*)d_in[6];
    const float* b1     = (const float*)d_in[7];
    const float* w2     = (const float*)d_in[8];
    const float* b2     = (const float*)d_in[9];
    const float* g1     = (const float*)d_in[10];
    const float* be1    = (const float*)d_in[11];
    const float* g2     = (const float*)d_in[12];
    const float* be2    = (const float*)d_in[13];
    float* out = (float*)d_out;

    // ---- R2-proven overlaid workspace plan (28,901,376 B) ----
    char* p = (char*)d_ws;
    auto alloc = [&](size_t bytes) {
        void* r = (void*)p;
        p += (bytes + 255) & ~(size_t)255;
        return r;
    };
    const size_t ACT  = (size_t)BT * CC * 2;      // 6291456 B, one bf16 activation
    bf16_t* wqt    = (bf16_t*)alloc(HH * HS * CC * 2);
    bf16_t* wkt    = (bf16_t*)alloc(HH * HS * CC * 2);
    bf16_t* wvt    = (bf16_t*)alloc(HH * HS * CC * 2);
    bf16_t* wpt    = (bf16_t*)alloc(CC * CC * 2);
    bf16_t* w1t    = (bf16_t*)alloc((size_t)C4 * CC * 2);
    bf16_t* w2t    = (bf16_t*)alloc((size_t)CC * C4 * 2);
    float*  colsum = (float*) alloc((size_t)24 * TT * 4);
    // slotA: h_bf (steps 2-3) -> attn (6-7) -> f1 chunk (9-10)
    char* slotA = (char*)alloc(ACT);
    // slotB: q_bf+k_bf (3-6) -> x1 fp32 (7-10)
    char* slotB = (char*)alloc(2 * ACT);
    // slotC: v_bf transposed (3-6) -> h2_bf (8-9)
    char* slotC = (char*)alloc(ACT);

    bf16_t* h_bf  = (bf16_t*)slotA;
    bf16_t* attn  = (bf16_t*)slotA;
    bf16_t* f1    = (bf16_t*)slotA;           // 2048 x 1536 bf16 chunk = 6291456 B
    bf16_t* q_bf  = (bf16_t*)slotB;
    bf16_t* k_bf  = (bf16_t*)(slotB + ACT);
    float*  x1    = (float*)slotB;            // 8192 x 384 fp32 = 12582912 B = 2*ACT
    bf16_t* v_bf  = (bf16_t*)slotC;           // [bh][d][t]
    bf16_t* h2_bf = (bf16_t*)slotC;

    // 1. weight transpose+cast
    tcast_kernel<<<(HH*CC*HS + 255)/256, 256, 0, stream>>>(wq, wqt, CC, HS, HH*CC*HS);
    tcast_kernel<<<(HH*CC*HS + 255)/256, 256, 0, stream>>>(wk, wkt, CC, HS, HH*CC*HS);
    tcast_kernel<<<(HH*CC*HS + 255)/256, 256, 0, stream>>>(wv, wvt, CC, HS, HH*CC*HS);
    tcast_kernel<<<(CC*CC + 255)/256, 256, 0, stream>>>(w_proj, wpt, CC, CC, CC*CC);
    tcast_kernel<<<(CC*C4 + 255)/256, 256, 0, stream>>>(w1, w1t, CC, C4, CC*C4);
    tcast_kernel<<<(C4*CC + 255)/256, 256, 0, stream>>>(w2, w2t, C4, CC, C4*CC);
    // 2. LN1
    ln_kernel<<<BT/4, 256, 0, stream>>>(x, g1, be1, h_bf);
    // 3. QKV
    qkv_kernel<<<dim3(BT/64, 18), 256, 0, stream>>>(h_bf, wqt, wkt, wvt, q_bf, k_bf, v_bf);
    // 4. column sums of exp(scores)
    colsum_kernel<<<dim3(32, 24), 256, 0, stream>>>(q_bf, k_bf, colsum);
    // 5. V /= colsum (in place)
    vscale_kernel<<<(24*HS*TT)/256, 256, 0, stream>>>(v_bf, colsum);
    // 6. attention output (reads q,k,v; writes attn=slotA, h dead)
    attn_out_kernel<<<dim3(32, 24), 256, 0, stream>>>(q_bf, k_bf, v_bf, attn);
    // 7. proj + bias + residual -> x1 (overlays q+k, both dead)
    gemm_kernel<CC, 0><<<dim3(BT/64, CC/64), 256, 0, stream>>>(attn, wpt, b_proj, x, x1, CC);
    // 8. LN2 -> h2 (overlays v, dead)
    ln_kernel<<<BT/4, 256, 0, stream>>>(x1, g2, be2, h2_bf);
    // 9+10. MLP in 4 row-chunks of 2048 (f1 chunk overlays attn, dead)
    for (int c = 0; c < 4; c++) {
        size_t m0 = (size_t)c * 2048;
        gemm_kernel<CC, 1><<<dim3(2048/64, C4/64), 256, 0, stream>>>(
            h2_bf + m0 * CC, w1t, b1, nullptr, f1, C4);
        gemm_kernel<C4, 0><<<dim3(2048/64, CC/64), 256, 0, stream>>>(
            f1, w2t, b2, x1 + m0 * CC, out + m0 * CC, CC);
    }
}